// Round 1
// baseline (3795.847 us; speedup 1.0000x reference)
//
#include <hip/hip_runtime.h>
#include <stdint.h>

#define D_MODEL 768
#define NHEAD 4
#define DHEAD 192
#define SEQ 1024
#define NLAYER 12
#define NTOK 4096
#define NVOCAB 50257

typedef __attribute__((ext_vector_type(4))) float f32x4;
typedef __attribute__((ext_vector_type(4))) int i32x4;

__device__ __forceinline__ unsigned short f2bf(float f) {
  unsigned u = __builtin_bit_cast(unsigned, f);
  u += 0x7FFFu + ((u >> 16) & 1u);
  return (unsigned short)(u >> 16);
}

// ---------------- embedding: h = tok_emb[x] + pos_emb ----------------
__global__ __launch_bounds__(256) void embed_kernel(
    const int* __restrict__ x, const float* __restrict__ tok,
    const float* __restrict__ pos, float* __restrict__ h) {
  int row = blockIdx.x;            // 0..4095  (b*1024 + t)
  int t = row & (SEQ - 1);
  int id = x[row];
  const float* tp = tok + (long)id * D_MODEL;
  const float* pp = pos + (long)t * D_MODEL;
  float* hp = h + (long)row * D_MODEL;
  for (int j = threadIdx.x; j < D_MODEL; j += 256)
    hp[j] = tp[j] + pp[j];
}

// ---------------- layernorm (f32 in) -> bf16 out ----------------
__global__ __launch_bounds__(256) void ln_kernel(
    const float* __restrict__ h, const float* __restrict__ sc,
    const float* __restrict__ sh, unsigned short* __restrict__ out) {
  __shared__ float red[4];
  int row = blockIdx.x;
  const float* x = h + (long)row * D_MODEL;
  int tid = threadIdx.x;
  float v0 = x[tid], v1 = x[tid + 256], v2 = x[tid + 512];
  float s = v0 + v1 + v2;
  for (int o = 32; o > 0; o >>= 1) s += __shfl_xor(s, o);
  if ((tid & 63) == 0) red[tid >> 6] = s;
  __syncthreads();
  float mean = (red[0] + red[1] + red[2] + red[3]) * (1.0f / D_MODEL);
  __syncthreads();
  float d0 = v0 - mean, d1 = v1 - mean, d2 = v2 - mean;
  float q = d0 * d0 + d1 * d1 + d2 * d2;
  for (int o = 32; o > 0; o >>= 1) q += __shfl_xor(q, o);
  if ((tid & 63) == 0) red[tid >> 6] = q;
  __syncthreads();
  float var = (red[0] + red[1] + red[2] + red[3]) * (1.0f / D_MODEL);
  float r = rsqrtf(var + 1e-5f);
  unsigned short* op = out + (long)row * D_MODEL;
  op[tid]       = f2bf(d0 * r * sc[tid]       + sh[tid]);
  op[tid + 256] = f2bf(d1 * r * sc[tid + 256] + sh[tid + 256]);
  op[tid + 512] = f2bf(d2 * r * sc[tid + 512] + sh[tid + 512]);
}

// ---------------- weight transpose: f32 [K][N] -> bf16 [N][K] ----------------
__global__ __launch_bounds__(256) void wtrans_kernel(
    const float* __restrict__ w, unsigned short* __restrict__ wt, int K, int N) {
  __shared__ unsigned short tile[32][33];
  int n0 = blockIdx.x * 32, k0 = blockIdx.y * 32;
  int tx = threadIdx.x, ty = threadIdx.y;   // 32 x 8
  int n = n0 + tx; if (n >= N) n = N - 1;   // clamp (head tail)
  #pragma unroll
  for (int i = 0; i < 4; ++i) {
    int k = k0 + ty + i * 8;
    tile[ty + i * 8][tx] = f2bf(w[(long)k * N + n]);
  }
  __syncthreads();
  #pragma unroll
  for (int i = 0; i < 4; ++i) {
    int nn = n0 + ty + i * 8;
    if (nn < N) wt[(long)nn * K + k0 + tx] = tile[tx][ty + i * 8];
  }
}

// ---------------- V transpose: qkv bf16 -> vt[bh][DHEAD][SEQ] ----------------
__global__ __launch_bounds__(256) void vt_kernel(
    const unsigned short* __restrict__ qkv, unsigned short* __restrict__ vt) {
  __shared__ unsigned short tile[32][33];
  int bh = blockIdx.z, b = bh >> 2, hh = bh & 3;
  int t0 = blockIdx.x * 32, f0 = blockIdx.y * 32;
  int tx = threadIdx.x, ty = threadIdx.y;
  const unsigned short* src = qkv + (long)b * SEQ * 2304 + 2 * D_MODEL + hh * DHEAD;
  #pragma unroll
  for (int i = 0; i < 4; ++i) {
    int t = t0 + ty + i * 8;
    tile[ty + i * 8][tx] = src[(long)t * 2304 + f0 + tx];
  }
  __syncthreads();
  unsigned short* dst = vt + (long)bh * DHEAD * SEQ;
  #pragma unroll
  for (int i = 0; i < 4; ++i) {
    int f = f0 + ty + i * 8;
    dst[(long)f * SEQ + t0 + tx] = tile[tx][ty + i * 8];
  }
}

// ---------------- causal row softmax: S f32 -> P bf16 (normalized) ----------------
__global__ __launch_bounds__(256) void softmax_kernel(
    const float* __restrict__ S, unsigned short* __restrict__ P) {
  __shared__ float red[4];
  long rid = blockIdx.x;            // bh*1024 + q
  int q = (int)(rid & (SEQ - 1));
  const float* s = S + rid * SEQ;
  unsigned short* p = P + rid * SEQ;
  int tid = threadIdx.x;
  int cnt = q + 1;
  float m = -3.0e38f;
  for (int i = tid; i < cnt; i += 256) m = fmaxf(m, s[i]);
  for (int o = 32; o > 0; o >>= 1) m = fmaxf(m, __shfl_xor(m, o));
  if ((tid & 63) == 0) red[tid >> 6] = m;
  __syncthreads();
  m = fmaxf(fmaxf(red[0], red[1]), fmaxf(red[2], red[3]));
  __syncthreads();
  float sum = 0.f;
  for (int i = tid; i < cnt; i += 256) sum += __expf(s[i] - m);
  for (int o = 32; o > 0; o >>= 1) sum += __shfl_xor(sum, o);
  if ((tid & 63) == 0) red[tid >> 6] = sum;
  __syncthreads();
  float inv = 1.0f / (red[0] + red[1] + red[2] + red[3]);
  for (int i = tid; i < cnt; i += 256) p[i] = f2bf(__expf(s[i] - m) * inv);
  for (int i = cnt + tid; i < SEQ; i += 256) p[i] = 0;
}

// ---------------- GEMM: C = A[M][K](bf16) x Bt[N][K](bf16), epilogue by MODE ----
// MODE 0: bf16 = acc + bias        (QKV)
// MODE 1: bf16 = relu(acc + bias)  (FC)
// MODE 2: f32  = acc * alpha       (S scores)
// MODE 3: f32 += acc + bias        (PV -> h, PROJ -> h)
// MODE 4: f32  = acc + bias        (head)
// causal: 0 none, 1 skip upper-tri N-blocks (S), 2 limit K to m0+BM (PV)
#define BM 128
#define BN 128
#define BKK 32

template<int MODE>
__global__ __launch_bounds__(256) void gemm_kernel(
    const unsigned short* __restrict__ A, int lda,
    const unsigned short* __restrict__ B, int ldb,
    const float* __restrict__ bias,
    void* __restrict__ Cv, int ldc,
    int M, int N, int K,
    int NI, long sAo, long sAi, long sBo, long sBi,
    long sCo, long sCi, float alpha, int causal) {
  __shared__ __align__(16) unsigned short As[BM * BKK];
  __shared__ __align__(16) unsigned short Bs[BN * BKK];
  int z = blockIdx.z;
  int zo = z / NI, zi = z - zo * NI;
  A += zo * sAo + zi * sAi;
  B += zo * sBo + zi * sBi;
  long coff = zo * sCo + zi * sCi;

  int m0 = blockIdx.y * BM;
  int n0 = blockIdx.x * BN;
  if (causal == 1 && n0 > m0 + BM - 1) return;
  int kmax = (causal == 2) ? min(K, m0 + BM) : K;

  int tid = threadIdx.x;
  int lane = tid & 63;
  int wave = tid >> 6;
  int wm = (wave >> 1) * 64;
  int wn = (wave & 1) * 64;

  f32x4 acc[4][4] = {};

  for (int k0 = 0; k0 < kmax; k0 += BKK) {
    __syncthreads();
    #pragma unroll
    for (int i = 0; i < 2; ++i) {
      int cc = i * 256 + tid;          // 16B chunk id, 512 total
      int row = cc >> 2;               // 64B per row (BKK bf16)
      int ko = (cc & 3) << 3;
      *(i32x4*)(As + row * BKK + ko) =
          *(const i32x4*)(A + (long)(m0 + row) * lda + k0 + ko);
      int rg = n0 + row; if (rg >= N) rg = N - 1;
      *(i32x4*)(Bs + row * BKK + ko) =
          *(const i32x4*)(B + (long)rg * ldb + k0 + ko);
    }
    __syncthreads();
    int lr = lane & 15;
    int kg = (lane >> 4) << 3;
    i32x4 af[4], bf[4];
    #pragma unroll
    for (int mi = 0; mi < 4; ++mi)
      af[mi] = *(const i32x4*)(As + (wm + mi * 16 + lr) * BKK + kg);
    #pragma unroll
    for (int ni = 0; ni < 4; ++ni)
      bf[ni] = *(const i32x4*)(Bs + (wn + ni * 16 + lr) * BKK + kg);
    #pragma unroll
    for (int mi = 0; mi < 4; ++mi)
      #pragma unroll
      for (int ni = 0; ni < 4; ++ni)
        asm("v_mfma_f32_16x16x32_bf16 %0, %1, %2, %0"
            : "+v"(acc[mi][ni]) : "v"(af[mi]), "v"(bf[ni]));
  }

  int cr = (lane >> 4) << 2;
  int cn = lane & 15;
  #pragma unroll
  for (int mi = 0; mi < 4; ++mi) {
    #pragma unroll
    for (int ni = 0; ni < 4; ++ni) {
      int col = n0 + wn + ni * 16 + cn;
      if (col >= N) continue;
      float bv = (MODE == 2) ? 0.f : (bias ? bias[col] : 0.f);
      #pragma unroll
      for (int r = 0; r < 4; ++r) {
        long row = m0 + wm + mi * 16 + cr + r;
        float v = acc[mi][ni][r] * alpha + bv;
        long idx = coff + row * ldc + col;
        if (MODE == 0)      ((unsigned short*)Cv)[idx] = f2bf(v);
        else if (MODE == 1) ((unsigned short*)Cv)[idx] = f2bf(fmaxf(v, 0.f));
        else if (MODE == 2) ((float*)Cv)[idx] = v;
        else if (MODE == 3) ((float*)Cv)[idx] += v;
        else                ((float*)Cv)[idx] = v;
      }
    }
  }
}

extern "C" void kernel_launch(void* const* d_in, const int* in_sizes, int n_in,
                              void* d_out, int out_size, void* d_ws, size_t ws_size,
                              hipStream_t stream) {
  const int*   x       = (const int*)  d_in[0];
  const float* tok_emb = (const float*)d_in[1];
  const float* pos_emb = (const float*)d_in[2];
  const float* ln1_s   = (const float*)d_in[3];
  const float* ln1_b   = (const float*)d_in[4];
  const float* qkv_w   = (const float*)d_in[5];
  const float* qkv_b   = (const float*)d_in[6];
  const float* ln2_s   = (const float*)d_in[7];
  const float* ln2_b   = (const float*)d_in[8];
  const float* fc_w    = (const float*)d_in[9];
  const float* fc_b    = (const float*)d_in[10];
  const float* proj_w  = (const float*)d_in[11];
  const float* proj_b  = (const float*)d_in[12];
  const float* lnf_s   = (const float*)d_in[13];
  const float* lnf_b   = (const float*)d_in[14];
  const float* head_w  = (const float*)d_in[15];
  const float* head_b  = (const float*)d_in[16];

  char* ws = (char*)d_ws;
  size_t off = 0;
  auto alloc = [&](size_t bytes) {
    char* p = ws + off;
    off += (bytes + 255) & ~(size_t)255;
    return p;
  };
  float*          h   = (float*)         alloc((size_t)NTOK * D_MODEL * 4);
  unsigned short* lnb = (unsigned short*)alloc((size_t)NTOK * D_MODEL * 2);
  unsigned short* qkv = (unsigned short*)alloc((size_t)NTOK * 2304 * 2);
  unsigned short* vt  = (unsigned short*)alloc((size_t)16 * DHEAD * SEQ * 2);
  unsigned short* mid = (unsigned short*)alloc((size_t)NTOK * 3072 * 2);
  float*          S   = (float*)         alloc((size_t)16 * SEQ * SEQ * 4);
  unsigned short* P   = (unsigned short*)alloc((size_t)16 * SEQ * SEQ * 2);
  unsigned short* wtq = (unsigned short*)alloc((size_t)2304 * 768 * 2);
  unsigned short* wtf = (unsigned short*)alloc((size_t)3072 * 768 * 2);
  unsigned short* wtp = (unsigned short*)alloc((size_t)768 * 3072 * 2);
  unsigned short* wth = (unsigned short*)alloc((size_t)50304 * 768 * 2);

  embed_kernel<<<NTOK, 256, 0, stream>>>(x, tok_emb, pos_emb, h);

  const float rscale = 0.07216878364870323f;  // 1/sqrt(192)

  for (int l = 0; l < NLAYER; ++l) {
    // ---- attention ----
    wtrans_kernel<<<dim3(72, 24), dim3(32, 8), 0, stream>>>(
        qkv_w + (long)l * 768 * 2304, wtq, 768, 2304);
    ln_kernel<<<NTOK, 256, 0, stream>>>(h, ln1_s + l * 768, ln1_b + l * 768, lnb);
    gemm_kernel<0><<<dim3(18, 32, 1), 256, 0, stream>>>(
        lnb, 768, wtq, 768, qkv_b + l * 2304, qkv, 2304,
        4096, 2304, 768, 1, 0, 0, 0, 0, 0, 0, 1.0f, 0);
    vt_kernel<<<dim3(32, 6, 16), dim3(32, 8), 0, stream>>>(qkv, vt);
    // S = scale * Q K^T   (batched over 16 (b,h); skip upper-tri blocks)
    gemm_kernel<2><<<dim3(8, 8, 16), 256, 0, stream>>>(
        qkv, 2304, qkv + 768, 2304, nullptr, S, 1024,
        1024, 1024, 192, 4,
        (long)1024 * 2304, 192, (long)1024 * 2304, 192,
        (long)4 * 1024 * 1024, (long)1024 * 1024, rscale, 1);
    softmax_kernel<<<16384, 256, 0, stream>>>(S, P);
    // h += P V   (k-limited by causality)
    gemm_kernel<3><<<dim3(2, 8, 16), 256, 0, stream>>>(
        P, 1024, vt, 1024, nullptr, h, 768,
        1024, 192, 1024, 4,
        (long)4 * 1024 * 1024, (long)1024 * 1024,
        (long)4 * 192 * 1024, (long)192 * 1024,
        (long)1024 * 768, 192, 1.0f, 2);
    // ---- MLP ----
    wtrans_kernel<<<dim3(96, 24), dim3(32, 8), 0, stream>>>(
        fc_w + (long)l * 768 * 3072, wtf, 768, 3072);
    ln_kernel<<<NTOK, 256, 0, stream>>>(h, ln2_s + l * 768, ln2_b + l * 768, lnb);
    gemm_kernel<1><<<dim3(24, 32, 1), 256, 0, stream>>>(
        lnb, 768, wtf, 768, fc_b + l * 3072, mid, 3072,
        4096, 3072, 768, 1, 0, 0, 0, 0, 0, 0, 1.0f, 0);
    wtrans_kernel<<<dim3(24, 96), dim3(32, 8), 0, stream>>>(
        proj_w + (long)l * 3072 * 768, wtp, 3072, 768);
    gemm_kernel<3><<<dim3(6, 32, 1), 256, 0, stream>>>(
        mid, 3072, wtp, 3072, proj_b + l * 768, h, 768,
        4096, 768, 3072, 1, 0, 0, 0, 0, 0, 0, 1.0f, 0);
  }

  // ---- final LN + head ----
  wtrans_kernel<<<dim3(1571, 24), dim3(32, 8), 0, stream>>>(head_w, wth, 768, 50257);
  ln_kernel<<<NTOK, 256, 0, stream>>>(h, lnf_s, lnf_b, lnb);
  gemm_kernel<4><<<dim3(393, 32, 1), 256, 0, stream>>>(
      lnb, 768, wth, 768, head_b, (float*)d_out, 50257,
      4096, 50257, 768, 1, 0, 0, 0, 0, 0, 0, 1.0f, 0);
}

// Round 2
// 3549.561 us; speedup vs baseline: 1.0694x; 1.0694x over previous
//
#include <hip/hip_runtime.h>
#include <stdint.h>

#define D_MODEL 768
#define NHEAD 4
#define DHEAD 192
#define SEQ 1024
#define NLAYER 12
#define NTOK 4096
#define NVOCAB 50257

typedef __attribute__((ext_vector_type(4))) float f32x4;
typedef __attribute__((ext_vector_type(4))) int i32x4;
typedef __attribute__((ext_vector_type(4))) unsigned short u16x4;

__device__ __forceinline__ unsigned short f2bf(float f) {
  unsigned u = __builtin_bit_cast(unsigned, f);
  u += 0x7FFFu + ((u >> 16) & 1u);
  return (unsigned short)(u >> 16);
}

// async global->LDS, 16B per lane; lds base must be wave-uniform
#define GLDS(src, dst)                                                   \
  __builtin_amdgcn_global_load_lds(                                      \
      (const __attribute__((address_space(1))) void*)(src),              \
      (__attribute__((address_space(3))) void*)(dst), 16, 0, 0)

// ---------------- embedding: h = tok_emb[x] + pos_emb ----------------
__global__ __launch_bounds__(256) void embed_kernel(
    const int* __restrict__ x, const float* __restrict__ tok,
    const float* __restrict__ pos, float* __restrict__ h) {
  int row = blockIdx.x;
  int t = row & (SEQ - 1);
  int id = x[row];
  const float* tp = tok + (long)id * D_MODEL;
  const float* pp = pos + (long)t * D_MODEL;
  float* hp = h + (long)row * D_MODEL;
  for (int j = threadIdx.x; j < D_MODEL; j += 256)
    hp[j] = tp[j] + pp[j];
}

// ---------------- layernorm (f32 in) -> bf16 out ----------------
__global__ __launch_bounds__(256) void ln_kernel(
    const float* __restrict__ h, const float* __restrict__ sc,
    const float* __restrict__ sh, unsigned short* __restrict__ out) {
  __shared__ float red[4];
  int row = blockIdx.x;
  const float* x = h + (long)row * D_MODEL;
  int tid = threadIdx.x;
  float v0 = x[tid], v1 = x[tid + 256], v2 = x[tid + 512];
  float s = v0 + v1 + v2;
  for (int o = 32; o > 0; o >>= 1) s += __shfl_xor(s, o);
  if ((tid & 63) == 0) red[tid >> 6] = s;
  __syncthreads();
  float mean = (red[0] + red[1] + red[2] + red[3]) * (1.0f / D_MODEL);
  __syncthreads();
  float d0 = v0 - mean, d1 = v1 - mean, d2 = v2 - mean;
  float q = d0 * d0 + d1 * d1 + d2 * d2;
  for (int o = 32; o > 0; o >>= 1) q += __shfl_xor(q, o);
  if ((tid & 63) == 0) red[tid >> 6] = q;
  __syncthreads();
  float var = (red[0] + red[1] + red[2] + red[3]) * (1.0f / D_MODEL);
  float r = rsqrtf(var + 1e-5f);
  unsigned short* op = out + (long)row * D_MODEL;
  op[tid]       = f2bf(d0 * r * sc[tid]       + sh[tid]);
  op[tid + 256] = f2bf(d1 * r * sc[tid + 256] + sh[tid + 256]);
  op[tid + 512] = f2bf(d2 * r * sc[tid + 512] + sh[tid + 512]);
}

// ---------------- weight transpose: f32 [K][N] -> bf16 [N][K] ----------------
__global__ __launch_bounds__(256) void wtrans_kernel(
    const float* __restrict__ w, unsigned short* __restrict__ wt, int K, int N) {
  __shared__ unsigned short tile[32][33];
  int n0 = blockIdx.x * 32, k0 = blockIdx.y * 32;
  int tx = threadIdx.x, ty = threadIdx.y;   // 32 x 8
  int n = n0 + tx; if (n >= N) n = N - 1;
  #pragma unroll
  for (int i = 0; i < 4; ++i) {
    int k = k0 + ty + i * 8;
    tile[ty + i * 8][tx] = f2bf(w[(long)k * N + n]);
  }
  __syncthreads();
  #pragma unroll
  for (int i = 0; i < 4; ++i) {
    int nn = n0 + ty + i * 8;
    if (nn < N) wt[(long)nn * K + k0 + tx] = tile[tx][ty + i * 8];
  }
}

// ---------------- V transpose: qkv bf16 -> vt[bh][DHEAD][SEQ] ----------------
__global__ __launch_bounds__(256) void vt_kernel(
    const unsigned short* __restrict__ qkv, unsigned short* __restrict__ vt) {
  __shared__ unsigned short tile[32][33];
  int bh = blockIdx.z, b = bh >> 2, hh = bh & 3;
  int t0 = blockIdx.x * 32, f0 = blockIdx.y * 32;
  int tx = threadIdx.x, ty = threadIdx.y;
  const unsigned short* src = qkv + (long)b * SEQ * 2304 + 2 * D_MODEL + hh * DHEAD;
  #pragma unroll
  for (int i = 0; i < 4; ++i) {
    int t = t0 + ty + i * 8;
    tile[ty + i * 8][tx] = src[(long)t * 2304 + f0 + tx];
  }
  __syncthreads();
  unsigned short* dst = vt + (long)bh * DHEAD * SEQ;
  #pragma unroll
  for (int i = 0; i < 4; ++i) {
    int f = f0 + ty + i * 8;
    dst[(long)f * SEQ + t0 + tx] = tile[tx][ty + i * 8];
  }
}

// ------- causal row softmax, single pass: S f32 -> P bf16 (normalized) -------
__global__ __launch_bounds__(256) void softmax_kernel(
    const float* __restrict__ S, unsigned short* __restrict__ P) {
  __shared__ float red[4];
  long rid = blockIdx.x;            // bh*1024 + q
  int q = (int)(rid & (SEQ - 1));
  int tid = threadIdx.x;
  int i0 = tid * 4;
  f32x4 v = *(const f32x4*)(S + rid * SEQ + i0);
  float m = -3.0e38f;
  #pragma unroll
  for (int j = 0; j < 4; ++j) {
    if (i0 + j > q) v[j] = -3.0e38f;
    m = fmaxf(m, v[j]);
  }
  for (int o = 32; o > 0; o >>= 1) m = fmaxf(m, __shfl_xor(m, o));
  if ((tid & 63) == 0) red[tid >> 6] = m;
  __syncthreads();
  m = fmaxf(fmaxf(red[0], red[1]), fmaxf(red[2], red[3]));
  __syncthreads();
  float e[4];
  float sum = 0.f;
  #pragma unroll
  for (int j = 0; j < 4; ++j) {
    e[j] = (i0 + j > q) ? 0.f : __expf(v[j] - m);
    sum += e[j];
  }
  for (int o = 32; o > 0; o >>= 1) sum += __shfl_xor(sum, o);
  if ((tid & 63) == 0) red[tid >> 6] = sum;
  __syncthreads();
  float inv = 1.0f / (red[0] + red[1] + red[2] + red[3]);
  u16x4 out;
  #pragma unroll
  for (int j = 0; j < 4; ++j) out[j] = f2bf(e[j] * inv);
  *(u16x4*)(P + rid * SEQ + i0) = out;
}

// ---------------- GEMM: C = A[M][K](bf16) x Bt[N][K](bf16), epilogue by MODE ----
// MODE 0: bf16 = acc + bias        (QKV)
// MODE 1: bf16 = relu(acc + bias)  (FC)
// MODE 2: f32  = acc * alpha       (S scores)
// MODE 3: f32 += acc + bias        (PV -> h, PROJ -> h)
// MODE 4: f32  = acc + bias        (head)
// causal: 0 none, 1 skip upper-tri N-blocks (S), 2 limit K to m0+BM (PV)
// mblocks > 0: 1D grid, linear id = n_blk*mblocks + m_blk (m fastest),
//              XCD-chunked swizzle (gridDim.x % 8 == 0 required)
#define BM 128
#define BN 128
#define BKK 32

template<int MODE>
__global__ __launch_bounds__(256) void gemm_kernel(
    const unsigned short* __restrict__ A, int lda,
    const unsigned short* __restrict__ B, int ldb,
    const float* __restrict__ bias,
    void* __restrict__ Cv, int ldc,
    int M, int N, int K,
    int NI, long sAo, long sAi, long sBo, long sBi,
    long sCo, long sCi, float alpha, int causal, int mblocks) {
  __shared__ __align__(16) unsigned short As[BM * BKK];
  __shared__ __align__(16) unsigned short Bs[BN * BKK];
  int z = blockIdx.z;
  int zo = z / NI, zi = z - zo * NI;
  A += zo * sAo + zi * sAi;
  B += zo * sBo + zi * sBi;
  long coff = zo * sCo + zi * sCi;

  int m0, n0;
  if (mblocks > 0) {
    int bid = blockIdx.x;
    int qq = (int)gridDim.x >> 3;       // gridDim.x % 8 == 0
    bid = (bid & 7) * qq + (bid >> 3);  // XCD-chunked, bijective
    m0 = (bid % mblocks) * BM;
    n0 = (bid / mblocks) * BN;
  } else {
    m0 = blockIdx.y * BM;
    n0 = blockIdx.x * BN;
  }
  if (causal == 1 && n0 > m0 + BM - 1) return;
  int kmax = (causal == 2) ? min(K, m0 + BM) : K;

  int tid = threadIdx.x;
  int lane = tid & 63;
  int wave = tid >> 6;
  int wm = (wave >> 1) * 64;
  int wn = (wave & 1) * 64;

  f32x4 acc[4][4] = {};

  for (int k0 = 0; k0 < kmax; k0 += BKK) {
    __syncthreads();
    #pragma unroll
    for (int i = 0; i < 2; ++i) {
      int c0 = i * 256 + wave * 64;     // wave-uniform chunk base
      int cc = c0 + lane;               // 16B chunk id, 512 per buffer
      int row = cc >> 2;
      int ko = (cc & 3) << 3;
      GLDS(A + (long)(m0 + row) * lda + k0 + ko, As + c0 * 8);
      int rg = n0 + row; if (rg >= N) rg = N - 1;
      GLDS(B + (long)rg * ldb + k0 + ko, Bs + c0 * 8);
    }
    __syncthreads();
    int lr = lane & 15;
    int kg = (lane >> 4) << 3;
    i32x4 af[4], bf[4];
    #pragma unroll
    for (int mi = 0; mi < 4; ++mi)
      af[mi] = *(const i32x4*)(As + (wm + mi * 16 + lr) * BKK + kg);
    #pragma unroll
    for (int ni = 0; ni < 4; ++ni)
      bf[ni] = *(const i32x4*)(Bs + (wn + ni * 16 + lr) * BKK + kg);
    #pragma unroll
    for (int mi = 0; mi < 4; ++mi)
      #pragma unroll
      for (int ni = 0; ni < 4; ++ni)
        asm("v_mfma_f32_16x16x32_bf16 %0, %1, %2, %0"
            : "+v"(acc[mi][ni]) : "v"(af[mi]), "v"(bf[ni]));
  }

  int cr = (lane >> 4) << 2;
  int cn = lane & 15;
  #pragma unroll
  for (int mi = 0; mi < 4; ++mi) {
    #pragma unroll
    for (int ni = 0; ni < 4; ++ni) {
      int col = n0 + wn + ni * 16 + cn;
      if (col >= N) continue;
      float bv = (MODE == 2) ? 0.f : (bias ? bias[col] : 0.f);
      #pragma unroll
      for (int r = 0; r < 4; ++r) {
        long row = m0 + wm + mi * 16 + cr + r;
        float v = acc[mi][ni][r] * alpha + bv;
        long idx = coff + row * ldc + col;
        if (MODE == 0)      ((unsigned short*)Cv)[idx] = f2bf(v);
        else if (MODE == 1) ((unsigned short*)Cv)[idx] = f2bf(fmaxf(v, 0.f));
        else if (MODE == 2) ((float*)Cv)[idx] = v;
        else if (MODE == 3) ((float*)Cv)[idx] += v;
        else                ((float*)Cv)[idx] = v;
      }
    }
  }
}

extern "C" void kernel_launch(void* const* d_in, const int* in_sizes, int n_in,
                              void* d_out, int out_size, void* d_ws, size_t ws_size,
                              hipStream_t stream) {
  const int*   x       = (const int*)  d_in[0];
  const float* tok_emb = (const float*)d_in[1];
  const float* pos_emb = (const float*)d_in[2];
  const float* ln1_s   = (const float*)d_in[3];
  const float* ln1_b   = (const float*)d_in[4];
  const float* qkv_w   = (const float*)d_in[5];
  const float* qkv_b   = (const float*)d_in[6];
  const float* ln2_s   = (const float*)d_in[7];
  const float* ln2_b   = (const float*)d_in[8];
  const float* fc_w    = (const float*)d_in[9];
  const float* fc_b    = (const float*)d_in[10];
  const float* proj_w  = (const float*)d_in[11];
  const float* proj_b  = (const float*)d_in[12];
  const float* lnf_s   = (const float*)d_in[13];
  const float* lnf_b   = (const float*)d_in[14];
  const float* head_w  = (const float*)d_in[15];
  const float* head_b  = (const float*)d_in[16];

  char* ws = (char*)d_ws;
  size_t off = 0;
  auto alloc = [&](size_t bytes) {
    char* p = ws + off;
    off += (bytes + 255) & ~(size_t)255;
    return p;
  };
  float*          h   = (float*)         alloc((size_t)NTOK * D_MODEL * 4);
  unsigned short* lnb = (unsigned short*)alloc((size_t)NTOK * D_MODEL * 2);
  unsigned short* qkv = (unsigned short*)alloc((size_t)NTOK * 2304 * 2);
  unsigned short* vt  = (unsigned short*)alloc((size_t)16 * DHEAD * SEQ * 2);
  unsigned short* mid = (unsigned short*)alloc((size_t)NTOK * 3072 * 2);
  float*          S   = (float*)         alloc((size_t)16 * SEQ * SEQ * 4);
  unsigned short* P   = (unsigned short*)alloc((size_t)16 * SEQ * SEQ * 2);
  unsigned short* wtq = (unsigned short*)alloc((size_t)2304 * 768 * 2);
  unsigned short* wtf = (unsigned short*)alloc((size_t)3072 * 768 * 2);
  unsigned short* wtp = (unsigned short*)alloc((size_t)768 * 3072 * 2);
  unsigned short* wth = (unsigned short*)alloc((size_t)50304 * 768 * 2);

  embed_kernel<<<NTOK, 256, 0, stream>>>(x, tok_emb, pos_emb, h);

  const float rscale = 0.07216878364870323f;  // 1/sqrt(192)

  for (int l = 0; l < NLAYER; ++l) {
    // ---- attention ----
    wtrans_kernel<<<dim3(72, 24), dim3(32, 8), 0, stream>>>(
        qkv_w + (long)l * 768 * 2304, wtq, 768, 2304);
    ln_kernel<<<NTOK, 256, 0, stream>>>(h, ln1_s + l * 768, ln1_b + l * 768, lnb);
    gemm_kernel<0><<<dim3(18, 32, 1), 256, 0, stream>>>(
        lnb, 768, wtq, 768, qkv_b + l * 2304, qkv, 2304,
        4096, 2304, 768, 1, 0, 0, 0, 0, 0, 0, 1.0f, 0, 0);
    vt_kernel<<<dim3(32, 6, 16), dim3(32, 8), 0, stream>>>(qkv, vt);
    // S = scale * Q K^T   (batched over 16 (b,h); skip upper-tri blocks)
    gemm_kernel<2><<<dim3(8, 8, 16), 256, 0, stream>>>(
        qkv, 2304, qkv + 768, 2304, nullptr, S, 1024,
        1024, 1024, 192, 4,
        (long)1024 * 2304, 192, (long)1024 * 2304, 192,
        (long)4 * 1024 * 1024, (long)1024 * 1024, rscale, 1, 0);
    softmax_kernel<<<16384, 256, 0, stream>>>(S, P);
    // h += P V   (k-limited by causality)
    gemm_kernel<3><<<dim3(2, 8, 16), 256, 0, stream>>>(
        P, 1024, vt, 1024, nullptr, h, 768,
        1024, 192, 1024, 4,
        (long)4 * 1024 * 1024, (long)1024 * 1024,
        (long)4 * 192 * 1024, (long)192 * 1024,
        (long)1024 * 768, 192, 1.0f, 2, 0);
    // ---- MLP ----
    wtrans_kernel<<<dim3(96, 24), dim3(32, 8), 0, stream>>>(
        fc_w + (long)l * 768 * 3072, wtf, 768, 3072);
    ln_kernel<<<NTOK, 256, 0, stream>>>(h, ln2_s + l * 768, ln2_b + l * 768, lnb);
    gemm_kernel<1><<<dim3(24, 32, 1), 256, 0, stream>>>(
        lnb, 768, wtf, 768, fc_b + l * 3072, mid, 3072,
        4096, 3072, 768, 1, 0, 0, 0, 0, 0, 0, 1.0f, 0, 0);
    wtrans_kernel<<<dim3(24, 96), dim3(32, 8), 0, stream>>>(
        proj_w + (long)l * 3072 * 768, wtp, 3072, 768);
    gemm_kernel<3><<<dim3(6, 32, 1), 256, 0, stream>>>(
        mid, 3072, wtp, 3072, proj_b + l * 768, h, 768,
        4096, 768, 3072, 1, 0, 0, 0, 0, 0, 0, 1.0f, 0, 0);
  }

  // ---- final LN + head ----
  wtrans_kernel<<<dim3(1571, 24), dim3(32, 8), 0, stream>>>(head_w, wth, 768, 50257);
  ln_kernel<<<NTOK, 256, 0, stream>>>(h, lnf_s, lnf_b, lnb);
  // 1D grid, M-fast + XCD-chunked swizzle: each XCD sweeps whole N-panels,
  // head weight fetched from HBM ~once instead of ~once per M-block.
  gemm_kernel<4><<<dim3(393 * 32, 1, 1), 256, 0, stream>>>(
      lnb, 768, wth, 768, head_b, (float*)d_out, 50257,
      4096, 50257, 768, 1, 0, 0, 0, 0, 0, 0, 1.0f, 0, 32);
}